// Round 1
// baseline (1132.356 us; speedup 1.0000x reference)
//
#include <hip/hip_runtime.h>
#include <hip/hip_bf16.h>

#define B_ 2
#define T_ 2048
#define C_ 1024
#define H_ 16
#define DV_ 64
#define KW_ 31

// ---------------------------------------------------------------- conv
__global__ __launch_bounds__(256) void conv_kernel(
        const float* __restrict__ x, const float* __restrict__ w,
        const float* __restrict__ bias, float* __restrict__ out) {
    int idx = blockIdx.x * 256 + threadIdx.x;          // over B*T*C
    int c = idx & (C_ - 1);
    int t = (idx >> 10) & (T_ - 1);
    int b = idx >> 21;
    const float* xc = x + (size_t)b * T_ * C_ + c;
    const float* wc = w + c * KW_;
    float acc = bias[c];
#pragma unroll
    for (int k = 0; k < KW_; k++) {
        int tt = t + k - 15;
        if (tt >= 0 && tt < T_) acc = fmaf(xc[(size_t)tt * C_], wc[k], acc);
    }
    out[idx] = acc;
}

// ---------------------------------------------------------------- q/k proj
__global__ __launch_bounds__(256) void qk_kernel(
        const float* __restrict__ x,
        const float* __restrict__ qw, const float* __restrict__ qb,
        const float* __restrict__ kw, const float* __restrict__ kb,
        float* __restrict__ qo, float* __restrict__ ko) {
    int idx = blockIdx.x * 256 + threadIdx.x;          // over (B*T)*64
    int o = idx & 63;
    int row = idx >> 6;
    bool isq = o < 32;
    int oo = o & 31;
    const float* wrow = (isq ? qw : kw) + (size_t)oo * C_;
    const float* xrow = x + (size_t)row * C_;
    float acc = 0.f;
#pragma unroll 4
    for (int c4 = 0; c4 < C_; c4 += 4) {
        float4 xv = *(const float4*)(xrow + c4);
        float4 wv = *(const float4*)(wrow + c4);
        acc = fmaf(xv.x, wv.x, acc);
        acc = fmaf(xv.y, wv.y, acc);
        acc = fmaf(xv.z, wv.z, acc);
        acc = fmaf(xv.w, wv.w, acc);
    }
    acc += (isq ? qb : kb)[oo];
    (isq ? qo : ko)[(size_t)row * 32 + oo] = acc;
}

// ---------------------------------------------------------------- attention
// 128 query rows / block, 256 threads: thread = (rl 0..31, dq 0..7)
// rows t0 + rl*4 + r (r<4), dims dq*8 .. dq*8+7. Online softmax, scores
// recomputed in pass2 (2 FMA) instead of stored.
#define ATS 32
__global__ __launch_bounds__(256) void attn_kernel(
        const float* __restrict__ qbuf, const float* __restrict__ kbuf,
        const float* __restrict__ x, float* __restrict__ xatt) {
    int bh = blockIdx.y;
    int b = bh >> 4, h = bh & 15;
    int t0 = ((int)gridDim.x - 1 - (int)blockIdx.x) * 128;  // long tails first
    int tid = threadIdx.x;
    int dq = tid >> 5;          // 0..7
    int rl = tid & 31;          // 0..31
    int d0 = dq * 8;
    __shared__ float2 kt[ATS];
    __shared__ float vt[ATS][DV_];
    const float scale = 0.02209708691f;                 // 1/sqrt(2048)
    float q0s[4], q1s[4], m[4], l[4], acc[4][8];
#pragma unroll
    for (int r = 0; r < 4; r++) {
        int t = t0 + rl * 4 + r;
        float2 q2 = *(const float2*)(qbuf + (size_t)(b * T_ + t) * 32 + h * 2);
        q0s[r] = q2.x * scale;
        q1s[r] = q2.y * scale;
        m[r] = -1e30f; l[r] = 0.f;
#pragma unroll
        for (int d = 0; d < 8; d++) acc[r][d] = 0.f;
    }
    int nt = (t0 + 128) / ATS;
    for (int st = 0; st < nt; st++) {
        int s0 = st * ATS;
        if (tid < ATS)
            kt[tid] = *(const float2*)(kbuf + (size_t)(b * T_ + s0 + tid) * 32 + h * 2);
        {
            int s = tid >> 3;
            int d8 = (tid & 7) * 8;
            const float* vp = x + (size_t)(b * T_ + s0 + s) * C_ + h * DV_ + d8;
            *(float4*)&vt[s][d8] = *(const float4*)vp;
            *(float4*)&vt[s][d8 + 4] = *(const float4*)(vp + 4);
        }
        __syncthreads();
        // pass 1: per-row tile max
        float tm[4];
#pragma unroll
        for (int r = 0; r < 4; r++) tm[r] = -1e30f;
#pragma unroll
        for (int j = 0; j < ATS; j++) {
            float2 k2 = kt[j];
#pragma unroll
            for (int r = 0; r < 4; r++) {
                int t = t0 + rl * 4 + r;
                float s_ = fmaf(q0s[r], k2.x, q1s[r] * k2.y);
                s_ = (s0 + j <= t) ? s_ : -1e30f;
                tm[r] = fmaxf(tm[r], s_);
            }
        }
        float nm[4];
#pragma unroll
        for (int r = 0; r < 4; r++) {
            nm[r] = fmaxf(m[r], tm[r]);
            float corr = __expf(m[r] - nm[r]);
            l[r] *= corr;
#pragma unroll
            for (int d = 0; d < 8; d++) acc[r][d] *= corr;
            m[r] = nm[r];
        }
        // pass 2: exp + PV
#pragma unroll
        for (int j = 0; j < ATS; j++) {
            float2 k2 = kt[j];
            const float4* vp = (const float4*)&vt[j][d0];
            float4 v0 = vp[0], v1 = vp[1];
#pragma unroll
            for (int r = 0; r < 4; r++) {
                int t = t0 + rl * 4 + r;
                float s_ = fmaf(q0s[r], k2.x, q1s[r] * k2.y);
                s_ = (s0 + j <= t) ? s_ : -1e30f;
                float p = __expf(s_ - nm[r]);
                l[r] += p;
                acc[r][0] = fmaf(p, v0.x, acc[r][0]);
                acc[r][1] = fmaf(p, v0.y, acc[r][1]);
                acc[r][2] = fmaf(p, v0.z, acc[r][2]);
                acc[r][3] = fmaf(p, v0.w, acc[r][3]);
                acc[r][4] = fmaf(p, v1.x, acc[r][4]);
                acc[r][5] = fmaf(p, v1.y, acc[r][5]);
                acc[r][6] = fmaf(p, v1.z, acc[r][6]);
                acc[r][7] = fmaf(p, v1.w, acc[r][7]);
            }
        }
        __syncthreads();
    }
#pragma unroll
    for (int r = 0; r < 4; r++) {
        int t = t0 + rl * 4 + r;
        float inv = 1.f / l[r];
        float* op = xatt + (size_t)(b * T_ + t) * C_ + h * DV_ + d0;
        float4 o0 = make_float4(acc[r][0] * inv, acc[r][1] * inv,
                                acc[r][2] * inv, acc[r][3] * inv);
        float4 o1 = make_float4(acc[r][4] * inv, acc[r][5] * inv,
                                acc[r][6] * inv, acc[r][7] * inv);
        *(float4*)op = o0;
        *(float4*)(op + 4) = o1;
    }
}

// ---------------------------------------------------------------- GEMM  out = A(M,K) * W(N,K)^T
// 128x128 tile, 256 threads, 8x8 micro-tile, BK=16, transposed LDS staging.
// MODE 0: silu(z+bias)      (mem gate 1)
// MODE 1: comb epilogue     (mem gate 2 + combine + decay)
// MODE 2: z+bias            (out proj)
#define GBK 16
#define LSTR 132
template <int MODE>
__global__ __launch_bounds__(256) void gemm_kernel(
        const float* __restrict__ A, const float* __restrict__ W,
        const float* __restrict__ bias, float* __restrict__ out,
        const float* __restrict__ e0, const float* __restrict__ e1,
        const float* __restrict__ e2, const float* __restrict__ e3) {
    __shared__ float At[GBK][LSTR];
    __shared__ float Wt[GBK][LSTR];
    int tid = threadIdx.x;
    int i0 = blockIdx.y * 128;
    int j0 = blockIdx.x * 128;
    int tx = tid & 15, ty = tid >> 4;
    int lr = tid >> 2;              // 0..63
    int lk = (tid & 3) * 4;         // 0,4,8,12
    float acc[8][8];
#pragma unroll
    for (int i = 0; i < 8; i++)
#pragma unroll
        for (int j = 0; j < 8; j++) acc[i][j] = 0.f;

    for (int k0 = 0; k0 < C_; k0 += GBK) {
#pragma unroll
        for (int half = 0; half < 2; half++) {
            int r = lr + half * 64;
            float4 a = *(const float4*)(A + (size_t)(i0 + r) * C_ + k0 + lk);
            At[lk + 0][r] = a.x; At[lk + 1][r] = a.y;
            At[lk + 2][r] = a.z; At[lk + 3][r] = a.w;
            float4 wv = *(const float4*)(W + (size_t)(j0 + r) * C_ + k0 + lk);
            Wt[lk + 0][r] = wv.x; Wt[lk + 1][r] = wv.y;
            Wt[lk + 2][r] = wv.z; Wt[lk + 3][r] = wv.w;
        }
        __syncthreads();
#pragma unroll
        for (int k = 0; k < GBK; k++) {
            float av[8], wv[8];
            *(float4*)&av[0] = *(const float4*)&At[k][ty * 8];
            *(float4*)&av[4] = *(const float4*)&At[k][ty * 8 + 4];
            *(float4*)&wv[0] = *(const float4*)&Wt[k][tx * 8];
            *(float4*)&wv[4] = *(const float4*)&Wt[k][tx * 8 + 4];
#pragma unroll
            for (int i = 0; i < 8; i++)
#pragma unroll
                for (int j = 0; j < 8; j++)
                    acc[i][j] = fmaf(av[i], wv[j], acc[i][j]);
        }
        __syncthreads();
    }
    // epilogue
    float bv[8];
#pragma unroll
    for (int j = 0; j < 8; j++) bv[j] = bias[j0 + tx * 8 + j];
    float tdv[8];
    if (MODE == 1) {
#pragma unroll
        for (int j = 0; j < 8; j++) tdv[j] = e3[j0 + tx * 8 + j];
    }
#pragma unroll
    for (int ii = 0; ii < 8; ii++) {
        int i = i0 + ty * 8 + ii;
        size_t off = (size_t)i * C_ + j0 + tx * 8;
#pragma unroll
        for (int h4 = 0; h4 < 2; h4++) {
            float vo[4];
            float4 c0, c1, c2;
            if (MODE == 1) {
                c0 = *(const float4*)(e0 + off + h4 * 4);   // x_conv
                c1 = *(const float4*)(e1 + off + h4 * 4);   // x_att
                c2 = *(const float4*)(e2 + off + h4 * 4);   // x
            }
#pragma unroll
            for (int q = 0; q < 4; q++) {
                int j = h4 * 4 + q;
                float z = acc[ii][j] + bv[j];
                if (MODE == 0) {
                    z = z / (1.f + __expf(-z));
                } else if (MODE == 1) {
                    float xc = (q == 0 ? c0.x : q == 1 ? c0.y : q == 2 ? c0.z : c0.w);
                    float xa = (q == 0 ? c1.x : q == 1 ? c1.y : q == 2 ? c1.z : c1.w);
                    float xx = (q == 0 ? c2.x : q == 1 ? c2.y : q == 2 ? c2.z : c2.w);
                    float comb = xc + 0.5f * xa + 0.5f * z;
                    z = comb * tdv[j] + xx * (1.f - tdv[j]);
                }
                vo[q] = z;
            }
            *(float4*)(out + off + h4 * 4) = *(float4*)vo;
        }
    }
}

// ---------------------------------------------------------------- layernorm + residual
__global__ __launch_bounds__(256) void ln_kernel(
        const float* __restrict__ proj, const float* __restrict__ x,
        const float* __restrict__ g, const float* __restrict__ bb,
        float* __restrict__ out) {
    int row = blockIdx.x;
    int tid = threadIdx.x;
    const float* pr = proj + (size_t)row * C_;
    float4 v = *(const float4*)(pr + tid * 4);
    float s = v.x + v.y + v.z + v.w;
    float s2 = v.x * v.x + v.y * v.y + v.z * v.z + v.w * v.w;
#pragma unroll
    for (int off = 32; off > 0; off >>= 1) {
        s += __shfl_down(s, off);
        s2 += __shfl_down(s2, off);
    }
    __shared__ float ws0[4], ws1[4];
    int wid = tid >> 6;
    if ((tid & 63) == 0) { ws0[wid] = s; ws1[wid] = s2; }
    __syncthreads();
    s = ws0[0] + ws0[1] + ws0[2] + ws0[3];
    s2 = ws1[0] + ws1[1] + ws1[2] + ws1[3];
    float mu = s * (1.f / C_);
    float var = s2 * (1.f / C_) - mu * mu;
    float rs = rsqrtf(var + 1e-5f);
    int c = tid * 4;
    float4 xr = *(const float4*)(x + (size_t)row * C_ + c);
    float4 gg = *(const float4*)(g + c);
    float4 bv = *(const float4*)(bb + c);
    float4 o;
    o.x = (v.x - mu) * rs * gg.x + bv.x + xr.x;
    o.y = (v.y - mu) * rs * gg.y + bv.y + xr.y;
    o.z = (v.z - mu) * rs * gg.z + bv.z + xr.z;
    o.w = (v.w - mu) * rs * gg.w + bv.w + xr.w;
    *(float4*)(out + (size_t)row * C_ + c) = o;
}

// ---------------------------------------------------------------- launch
extern "C" void kernel_launch(void* const* d_in, const int* in_sizes, int n_in,
                              void* d_out, int out_size, void* d_ws, size_t ws_size,
                              hipStream_t stream) {
    const float* x      = (const float*)d_in[0];
    const float* conv_w = (const float*)d_in[1];
    const float* conv_b = (const float*)d_in[2];
    const float* q_w    = (const float*)d_in[3];
    const float* q_b    = (const float*)d_in[4];
    const float* kv_w   = (const float*)d_in[5];
    const float* kv_b   = (const float*)d_in[6];
    const float* mem_w1 = (const float*)d_in[7];
    const float* mem_b1 = (const float*)d_in[8];
    const float* mem_w2 = (const float*)d_in[9];
    const float* mem_b2 = (const float*)d_in[10];
    const float* out_w  = (const float*)d_in[11];
    const float* out_b  = (const float*)d_in[12];
    const float* ln_g   = (const float*)d_in[13];
    const float* ln_b   = (const float*)d_in[14];
    const float* td     = (const float*)d_in[15];
    float* out = (float*)d_out;
    float* ws  = (float*)d_ws;

    const size_t NTC = (size_t)B_ * T_ * C_;
    float* xconv = ws;
    float* qb_   = xconv + NTC;
    float* kb_   = qb_ + (size_t)B_ * T_ * 32;
    float* xatt  = kb_ + (size_t)B_ * T_ * 32;
    float* y1    = xatt + NTC;
    float* comb  = y1 + NTC;
    float* proj  = comb + NTC;

    conv_kernel<<<(int)(NTC / 256), 256, 0, stream>>>(x, conv_w, conv_b, xconv);
    qk_kernel<<<(B_ * T_ * 64) / 256, 256, 0, stream>>>(x, q_w, q_b, kv_w, kv_b, qb_, kb_);
    attn_kernel<<<dim3(T_ / 128, B_ * H_), 256, 0, stream>>>(qb_, kb_, x, xatt);
    gemm_kernel<0><<<dim3(C_ / 128, (B_ * T_) / 128), 256, 0, stream>>>(
        x, mem_w1, mem_b1, y1, nullptr, nullptr, nullptr, nullptr);
    gemm_kernel<1><<<dim3(C_ / 128, (B_ * T_) / 128), 256, 0, stream>>>(
        y1, mem_w2, mem_b2, comb, xconv, xatt, x, td);
    gemm_kernel<2><<<dim3(C_ / 128, (B_ * T_) / 128), 256, 0, stream>>>(
        comb, out_w, out_b, proj, nullptr, nullptr, nullptr, nullptr);
    ln_kernel<<<B_ * T_, 256, 0, stream>>>(proj, x, ln_g, ln_b, out);
}

// Round 2
// 478.030 us; speedup vs baseline: 2.3688x; 2.3688x over previous
//
#include <hip/hip_runtime.h>
#include <hip/hip_bf16.h>

#define B_ 2
#define T_ 2048
#define C_ 1024
#define H_ 16
#define DV_ 64
#define KW_ 31

typedef __attribute__((ext_vector_type(8))) short bf16x8;
typedef __attribute__((ext_vector_type(4))) float f32x4;

__device__ inline short f2bf(float f) {
    __hip_bfloat16 h = __float2bfloat16(f);
    return *reinterpret_cast<short*>(&h);
}

__device__ inline void async16(const void* g, void* l) {
    __builtin_amdgcn_global_load_lds(
        (const __attribute__((address_space(1))) unsigned int*)g,
        (__attribute__((address_space(3))) unsigned int*)l, 16, 0, 0);
}

// ---------------------------------------------------------------- conv (fp32)
__global__ __launch_bounds__(256) void conv_kernel(
        const float* __restrict__ x, const float* __restrict__ w,
        const float* __restrict__ bias, float* __restrict__ out) {
    int idx = blockIdx.x * 256 + threadIdx.x;
    int c = idx & (C_ - 1);
    int t = (idx >> 10) & (T_ - 1);
    int b = idx >> 21;
    const float* xc = x + (size_t)b * T_ * C_ + c;
    const float* wc = w + c * KW_;
    float acc = bias[c];
#pragma unroll
    for (int k = 0; k < KW_; k++) {
        int tt = t + k - 15;
        if (tt >= 0 && tt < T_) acc = fmaf(xc[(size_t)tt * C_], wc[k], acc);
    }
    out[idx] = acc;
}

// ---------------------------------------------------------------- q/k proj (fp32)
__global__ __launch_bounds__(256) void qk_kernel(
        const float* __restrict__ x,
        const float* __restrict__ qw, const float* __restrict__ qb,
        const float* __restrict__ kw, const float* __restrict__ kb,
        float* __restrict__ qo, float* __restrict__ ko) {
    int idx = blockIdx.x * 256 + threadIdx.x;
    int o = idx & 63;
    int row = idx >> 6;
    bool isq = o < 32;
    int oo = o & 31;
    const float* wrow = (isq ? qw : kw) + (size_t)oo * C_;
    const float* xrow = x + (size_t)row * C_;
    float acc = 0.f;
#pragma unroll 4
    for (int c4 = 0; c4 < C_; c4 += 4) {
        float4 xv = *(const float4*)(xrow + c4);
        float4 wv = *(const float4*)(wrow + c4);
        acc = fmaf(xv.x, wv.x, acc);
        acc = fmaf(xv.y, wv.y, acc);
        acc = fmaf(xv.z, wv.z, acc);
        acc = fmaf(xv.w, wv.w, acc);
    }
    acc += (isq ? qb : kb)[oo];
    (isq ? qo : ko)[(size_t)row * 32 + oo] = acc;
}

// ---------------------------------------------------------------- f32 -> bf16
__global__ __launch_bounds__(256) void cvt_kernel(
        const float* __restrict__ in, short* __restrict__ out) {
    int i = blockIdx.x * 256 + threadIdx.x;      // per 8 elems
    float4 v0 = ((const float4*)in)[i * 2];
    float4 v1 = ((const float4*)in)[i * 2 + 1];
    bf16x8 o;
    o[0] = f2bf(v0.x); o[1] = f2bf(v0.y); o[2] = f2bf(v0.z); o[3] = f2bf(v0.w);
    o[4] = f2bf(v1.x); o[5] = f2bf(v1.y); o[6] = f2bf(v1.z); o[7] = f2bf(v1.w);
    ((bf16x8*)out)[i] = o;
}

// ---------------------------------------------------------------- V transpose: x (B,T,C) -> xvt (B*H, 64, T) bf16
__global__ __launch_bounds__(256) void vtrans_kernel(
        const float* __restrict__ x, short* __restrict__ xvt) {
    int bh = blockIdx.y;
    int b = bh >> 4, h = bh & 15;
    int t0 = blockIdx.x * 64;
    __shared__ float ldsT[64][65];
    int tid = threadIdx.x;
    int tl = tid >> 2;
    int d0 = (tid & 3) * 16;
    const float* xp = x + ((size_t)(b * T_ + t0 + tl)) * C_ + h * 64 + d0;
#pragma unroll
    for (int q = 0; q < 4; q++) {
        float4 v = *(const float4*)(xp + q * 4);
        ldsT[d0 + q * 4 + 0][tl] = v.x;
        ldsT[d0 + q * 4 + 1][tl] = v.y;
        ldsT[d0 + q * 4 + 2][tl] = v.z;
        ldsT[d0 + q * 4 + 3][tl] = v.w;
    }
    __syncthreads();
    int d = tid >> 2;
    int ts = (tid & 3) * 16;
    short* op = xvt + ((size_t)bh * 64 + d) * T_ + t0 + ts;
    bf16x8 o0, o1;
#pragma unroll
    for (int q = 0; q < 8; q++) {
        o0[q] = f2bf(ldsT[d][ts + q]);
        o1[q] = f2bf(ldsT[d][ts + 8 + q]);
    }
    *(bf16x8*)op = o0;
    *(bf16x8*)(op + 8) = o1;
}

// ---------------------------------------------------------------- attention (MFMA PV)
// 128 q-rows/block, 256 thr. Softmax role: row=tid>>1, j-half=tid&1 (16 scores).
// MFMA role: wave w owns rows w*32..w*32+31 (P wave-local), all 64 dv cols.
__global__ __launch_bounds__(256) void attn_kernel(
        const float* __restrict__ qbuf, const float* __restrict__ kbuf,
        const short* __restrict__ xvt, float* __restrict__ xatt) {
    int bh = blockIdx.y;
    int b = bh >> 4, h = bh & 15;
    int t0 = ((int)gridDim.x - 1 - (int)blockIdx.x) * 128;
    int tid = threadIdx.x;
    int w = tid >> 6, l = tid & 63;

    __shared__ short P_lds[128 * 32];       // 8KB, slot-swizzled
    __shared__ short V_lds[2][64 * 32];     // 2x4KB, slot-swizzled
    __shared__ float2 kt[2][32];
    __shared__ float red_lds[128];          // corr, then l

    const float scale = 0.02209708691f;     // 1/sqrt(2048)
    int r = tid >> 1, jh = tid & 1;
    int tglob = t0 + r;
    float2 q2 = *(const float2*)(qbuf + ((size_t)(b * T_ + tglob)) * 32 + h * 2);
    float q0 = q2.x * scale, q1 = q2.y * scale;
    float mrun = -1e30f, lrun = 0.f;

    f32x4 acc[2][4];
#pragma unroll
    for (int m = 0; m < 2; m++)
#pragma unroll
        for (int n = 0; n < 4; n++) acc[m][n] = (f32x4){0.f, 0.f, 0.f, 0.f};

    int R0 = w * 32;
    const int xorb = (((l >> 4) ^ (l & 3)) << 4);
    char* Pb = (char*)P_lds;
    char* Vb = (char*)V_lds;

    // stage helpers
    int dl = l >> 2;                 // 0..15
    int d = w * 16 + dl;             // 0..63
    int chunk = l & 3;
    const char* vsrc_base = (const char*)xvt + (((size_t)bh * 64 + d) * T_) * 2
                            + (((chunk ^ (dl & 3)) << 3)) * 2;
    int nt = t0 / 32 + 4;

    // prologue: stage tile 0 into buf 0
    if (tid < 32) kt[0][tid] = *(const float2*)(kbuf + ((size_t)(b * T_ + tid)) * 32 + h * 2);
    async16(vsrc_base, Vb + w * 1024);

    for (int t = 0; t < nt; t++) {
        int buf = t & 1;
        __syncthreads();            // staged buf ready; prev MFMA done
        // prefetch next tile
        if (t + 1 < nt) {
            int s0n = (t + 1) * 32;
            if (tid < 32)
                kt[buf ^ 1][tid] = *(const float2*)(kbuf + ((size_t)(b * T_ + s0n + tid)) * 32 + h * 2);
            async16(vsrc_base + (size_t)s0n * 2, Vb + (buf ^ 1) * 4096 + w * 1024);
        }
        // ---- softmax role
        int s0 = t * 32;
        int jbase = jh * 16;
        float s_[16];
        float tm = -1e30f;
#pragma unroll
        for (int jj = 0; jj < 16; jj++) {
            float2 k2 = kt[buf][jbase + jj];
            float sc = fmaf(q0, k2.x, q1 * k2.y);
            sc = (s0 + jbase + jj <= tglob) ? sc : -1e30f;
            s_[jj] = sc;
            tm = fmaxf(tm, sc);
        }
        tm = fmaxf(tm, __shfl_xor(tm, 1));
        float nm = fmaxf(mrun, tm);
        float corr = __expf(mrun - nm);
        mrun = nm;
        float ls = 0.f;
        bf16x8 c0, c1;
#pragma unroll
        for (int jj = 0; jj < 8; jj++) {
            float p = __expf(s_[jj] - nm);
            ls += p;
            c0[jj] = f2bf(p);
        }
#pragma unroll
        for (int jj = 8; jj < 16; jj++) {
            float p = __expf(s_[jj] - nm);
            ls += p;
            c1[jj - 8] = f2bf(p);
        }
        ls += __shfl_xor(ls, 1);
        lrun = lrun * corr + ls;
        if (jh == 0) red_lds[r] = corr;
        int cw0 = jh * 2, cw1 = jh * 2 + 1;
        *(bf16x8*)(Pb + r * 64 + (((cw0 ^ (r & 3)) << 4))) = c0;
        *(bf16x8*)(Pb + r * 64 + (((cw1 ^ (r & 3)) << 4))) = c1;
        // ---- MFMA role (wave-local P/corr: no barrier needed)
#pragma unroll
        for (int m = 0; m < 2; m++) {
#pragma unroll
            for (int g = 0; g < 4; g++) {
                float cc = red_lds[R0 + m * 16 + ((l >> 4) << 2) + g];
#pragma unroll
                for (int n = 0; n < 4; n++) acc[m][n][g] *= cc;
            }
        }
        bf16x8 afr[2], bfr[4];
#pragma unroll
        for (int m = 0; m < 2; m++)
            afr[m] = *(const bf16x8*)(Pb + (R0 + m * 16 + (l & 15)) * 64 + xorb);
#pragma unroll
        for (int n = 0; n < 4; n++)
            bfr[n] = *(const bf16x8*)(Vb + buf * 4096 + (n * 16 + (l & 15)) * 64 + xorb);
#pragma unroll
        for (int m = 0; m < 2; m++)
#pragma unroll
            for (int n = 0; n < 4; n++)
                acc[m][n] = __builtin_amdgcn_mfma_f32_16x16x32_bf16(afr[m], bfr[n], acc[m][n], 0, 0, 0);
    }
    // epilogue
    if (jh == 0) red_lds[r] = lrun;
#pragma unroll
    for (int m = 0; m < 2; m++) {
#pragma unroll
        for (int g = 0; g < 4; g++) {
            int row = R0 + m * 16 + ((l >> 4) << 2) + g;
            float inv = 1.f / red_lds[row];
            int trow = t0 + row;
#pragma unroll
            for (int n = 0; n < 4; n++) {
                int col = h * 64 + n * 16 + (l & 15);
                xatt[((size_t)(b * T_ + trow)) * C_ + col] = acc[m][n][g] * inv;
            }
        }
    }
}

// ---------------------------------------------------------------- bf16 MFMA GEMM  out = A(M,K)*W(N,K)^T
// tile 128(M)x64(N), BK=32, 4 waves: wave w rows w*32..+31, all 64 cols.
// MODE 0: silu -> bf16 out.  MODE 1: comb epilogue -> bf16 out.  MODE 2: fp32 out.
template <int MODE>
__global__ __launch_bounds__(256) void mgemm_kernel(
        const short* __restrict__ A, const short* __restrict__ W,
        const float* __restrict__ bias, short* __restrict__ outb,
        float* __restrict__ out32,
        const float* __restrict__ e0, const float* __restrict__ e1,
        const float* __restrict__ e2, const float* __restrict__ e3) {
    __shared__ short At[128 * 32];
    __shared__ short Wt[64 * 32];
    int tid = threadIdx.x;
    int w = tid >> 6, l = tid & 63;
    int i0 = blockIdx.y * 128, j0 = blockIdx.x * 64;
    int R0 = w * 32;
    const int xorb = (((l >> 4) ^ (l & 3)) << 4);
    int srow = l >> 2, schunk = l & 3;

    f32x4 acc[2][4];
#pragma unroll
    for (int m = 0; m < 2; m++)
#pragma unroll
        for (int n = 0; n < 4; n++) acc[m][n] = (f32x4){0.f, 0.f, 0.f, 0.f};

    for (int k0 = 0; k0 < C_; k0 += 32) {
#pragma unroll
        for (int half = 0; half < 2; half++) {
            int rr = half * 64 + w * 16 + srow;
            int gch = schunk ^ (rr & 3);
            async16((const char*)(A + (size_t)(i0 + rr) * C_ + k0) + gch * 16,
                    (char*)At + half * 4096 + w * 1024);
        }
        {
            int rr = w * 16 + srow;
            int gch = schunk ^ (rr & 3);
            async16((const char*)(W + (size_t)(j0 + rr) * C_ + k0) + gch * 16,
                    (char*)Wt + w * 1024);
        }
        __syncthreads();
        bf16x8 afr[2], bfr[4];
#pragma unroll
        for (int m = 0; m < 2; m++)
            afr[m] = *(const bf16x8*)((char*)At + (R0 + m * 16 + (l & 15)) * 64 + xorb);
#pragma unroll
        for (int n = 0; n < 4; n++)
            bfr[n] = *(const bf16x8*)((char*)Wt + (n * 16 + (l & 15)) * 64 + xorb);
#pragma unroll
        for (int m = 0; m < 2; m++)
#pragma unroll
            for (int n = 0; n < 4; n++)
                acc[m][n] = __builtin_amdgcn_mfma_f32_16x16x32_bf16(afr[m], bfr[n], acc[m][n], 0, 0, 0);
        __syncthreads();
    }
    // epilogue
#pragma unroll
    for (int n = 0; n < 4; n++) {
        int col = j0 + n * 16 + (l & 15);
        float bj = bias[col];
        float tdv = (MODE == 1) ? e3[col] : 0.f;
#pragma unroll
        for (int m = 0; m < 2; m++) {
            int rbase = i0 + R0 + m * 16 + ((l >> 4) << 2);
#pragma unroll
            for (int g = 0; g < 4; g++) {
                size_t off = (size_t)(rbase + g) * C_ + col;
                float z = acc[m][n][g] + bj;
                if (MODE == 0) {
                    z = z / (1.f + __expf(-z));
                    outb[off] = f2bf(z);
                } else if (MODE == 1) {
                    float comb = e0[off] + 0.5f * e1[off] + 0.5f * z;
                    z = comb * tdv + e2[off] * (1.f - tdv);
                    outb[off] = f2bf(z);
                } else {
                    out32[off] = z;
                }
            }
        }
    }
}

// ---------------------------------------------------------------- layernorm + residual
__global__ __launch_bounds__(256) void ln_kernel(
        const float* __restrict__ proj, const float* __restrict__ x,
        const float* __restrict__ g, const float* __restrict__ bb,
        float* __restrict__ out) {
    int row = blockIdx.x;
    int tid = threadIdx.x;
    const float* pr = proj + (size_t)row * C_;
    float4 v = *(const float4*)(pr + tid * 4);
    float s = v.x + v.y + v.z + v.w;
    float s2 = v.x * v.x + v.y * v.y + v.z * v.z + v.w * v.w;
#pragma unroll
    for (int off = 32; off > 0; off >>= 1) {
        s += __shfl_down(s, off);
        s2 += __shfl_down(s2, off);
    }
    __shared__ float ws0[4], ws1[4];
    int wid = tid >> 6;
    if ((tid & 63) == 0) { ws0[wid] = s; ws1[wid] = s2; }
    __syncthreads();
    s = ws0[0] + ws0[1] + ws0[2] + ws0[3];
    s2 = ws1[0] + ws1[1] + ws1[2] + ws1[3];
    float mu = s * (1.f / C_);
    float var = s2 * (1.f / C_) - mu * mu;
    float rs = rsqrtf(var + 1e-5f);
    int c = tid * 4;
    float4 xr = *(const float4*)(x + (size_t)row * C_ + c);
    float4 gg = *(const float4*)(g + c);
    float4 bv = *(const float4*)(bb + c);
    float4 o;
    o.x = (v.x - mu) * rs * gg.x + bv.x + xr.x;
    o.y = (v.y - mu) * rs * gg.y + bv.y + xr.y;
    o.z = (v.z - mu) * rs * gg.z + bv.z + xr.z;
    o.w = (v.w - mu) * rs * gg.w + bv.w + xr.w;
    *(float4*)(out + (size_t)row * C_ + c) = o;
}

// ---------------------------------------------------------------- launch
extern "C" void kernel_launch(void* const* d_in, const int* in_sizes, int n_in,
                              void* d_out, int out_size, void* d_ws, size_t ws_size,
                              hipStream_t stream) {
    const float* x      = (const float*)d_in[0];
    const float* conv_w = (const float*)d_in[1];
    const float* conv_b = (const float*)d_in[2];
    const float* q_w    = (const float*)d_in[3];
    const float* q_b    = (const float*)d_in[4];
    const float* kv_w   = (const float*)d_in[5];
    const float* kv_b   = (const float*)d_in[6];
    const float* mem_w1 = (const float*)d_in[7];
    const float* mem_b1 = (const float*)d_in[8];
    const float* mem_w2 = (const float*)d_in[9];
    const float* mem_b2 = (const float*)d_in[10];
    const float* out_w  = (const float*)d_in[11];
    const float* out_b  = (const float*)d_in[12];
    const float* ln_g   = (const float*)d_in[13];
    const float* ln_b   = (const float*)d_in[14];
    const float* td     = (const float*)d_in[15];
    float* out = (float*)d_out;

    const size_t NTC = (size_t)B_ * T_ * C_;      // 4M
    char* p = (char*)d_ws;
    float* xconv = (float*)p;            p += NTC * 4;
    float* xatt  = (float*)p;            p += NTC * 4;
    float* proj  = (float*)p;            p += NTC * 4;
    float* qb_   = (float*)p;            p += (size_t)B_ * T_ * 32 * 4;
    float* kb_   = (float*)p;            p += (size_t)B_ * T_ * 32 * 4;
    short* xbf   = (short*)p;            p += NTC * 2;
    short* y1bf  = (short*)p;            p += NTC * 2;
    short* combbf= (short*)p;            p += NTC * 2;
    short* xvt   = (short*)p;            p += NTC * 2;
    short* wbf1  = (short*)p;            p += (size_t)C_ * C_ * 2;
    short* wbf2  = (short*)p;            p += (size_t)C_ * C_ * 2;
    short* wbf3  = (short*)p;            p += (size_t)C_ * C_ * 2;

    const int WN8 = (C_ * C_) / 8 / 256;          // weight convert grid
    cvt_kernel<<<(int)(NTC / 8 / 256), 256, 0, stream>>>(x, xbf);
    cvt_kernel<<<WN8, 256, 0, stream>>>(mem_w1, wbf1);
    cvt_kernel<<<WN8, 256, 0, stream>>>(mem_w2, wbf2);
    cvt_kernel<<<WN8, 256, 0, stream>>>(out_w, wbf3);
    vtrans_kernel<<<dim3(T_ / 64, B_ * H_), 256, 0, stream>>>(x, xvt);
    conv_kernel<<<(int)(NTC / 256), 256, 0, stream>>>(x, conv_w, conv_b, xconv);
    qk_kernel<<<(B_ * T_ * 64) / 256, 256, 0, stream>>>(x, q_w, q_b, kv_w, kv_b, qb_, kb_);
    attn_kernel<<<dim3(T_ / 128, B_ * H_), 256, 0, stream>>>(qb_, kb_, xvt, xatt);
    mgemm_kernel<0><<<dim3(C_ / 64, (B_ * T_) / 128), 256, 0, stream>>>(
        xbf, wbf1, mem_b1, y1bf, nullptr, nullptr, nullptr, nullptr, nullptr);
    mgemm_kernel<1><<<dim3(C_ / 64, (B_ * T_) / 128), 256, 0, stream>>>(
        y1bf, wbf2, mem_b2, combbf, nullptr, xconv, xatt, x, td);
    mgemm_kernel<2><<<dim3(C_ / 64, (B_ * T_) / 128), 256, 0, stream>>>(
        combbf, wbf3, out_b, nullptr, proj, nullptr, nullptr, nullptr, nullptr);
    ln_kernel<<<B_ * T_, 256, 0, stream>>>(proj, x, ln_g, ln_b, out);
}

// Round 3
// 212.923 us; speedup vs baseline: 5.3181x; 2.2451x over previous
//
#include <hip/hip_runtime.h>
#include <hip/hip_bf16.h>

#define B_ 2
#define T_ 2048
#define C_ 1024
#define H_ 16
#define DV_ 64
#define KW_ 31

typedef __attribute__((ext_vector_type(8))) short bf16x8;
typedef __attribute__((ext_vector_type(4))) float f32x4;

__device__ inline short f2bf(float f) {
    __hip_bfloat16 h = __float2bfloat16(f);
    return *reinterpret_cast<short*>(&h);
}

__device__ inline void async16(const void* g, void* l) {
    __builtin_amdgcn_global_load_lds(
        (const __attribute__((address_space(1))) unsigned int*)g,
        (__attribute__((address_space(3))) unsigned int*)l, 16, 0, 0);
}

// ---------------------------------------------------------------- conv (register sliding window)
// block: 256 channels x 1 batch x TCV time-steps. Weights staged LDS->regs.
#define TCV 32
__global__ __launch_bounds__(256) void conv_kernel(
        const float* __restrict__ x, const float* __restrict__ w,
        const float* __restrict__ bias, float* __restrict__ out) {
    int b = blockIdx.y >> 2;
    int c0 = (blockIdx.y & 3) * 256;
    int t0 = blockIdx.x * TCV;
    int tid = threadIdx.x;
    __shared__ float wl[256 * KW_];
    for (int i = tid; i < 256 * KW_; i += 256) wl[i] = w[c0 * KW_ + i];
    __syncthreads();
    float wr[KW_];
#pragma unroll
    for (int k = 0; k < KW_; k++) wr[k] = wl[tid * KW_ + k];
    int c = c0 + tid;
    float bi = bias[c];
    float acc[TCV];
#pragma unroll
    for (int t = 0; t < TCV; t++) acc[t] = bi;
    const float* xp = x + (size_t)b * T_ * C_ + c;
#pragma unroll
    for (int i = 0; i < TCV + KW_ - 1; i++) {
        int tt = t0 + i - 15;
        float xv = (tt >= 0 && tt < T_) ? xp[(size_t)tt * C_] : 0.f;
        int lo = (i - (KW_ - 1) > 0) ? i - (KW_ - 1) : 0;
        int hi = (i < TCV - 1) ? i : TCV - 1;
#pragma unroll
        for (int t = lo; t <= hi; t++)
            acc[t] = fmaf(xv, wr[i - t], acc[t]);
    }
    float* op = out + ((size_t)b * T_ + t0) * C_ + c;
#pragma unroll
    for (int t = 0; t < TCV; t++) op[(size_t)t * C_] = acc[t];
}

// ---------------------------------------------------------------- f32 -> bf16
__global__ __launch_bounds__(256) void cvt_kernel(
        const float* __restrict__ in, short* __restrict__ out) {
    int i = blockIdx.x * 256 + threadIdx.x;      // per 8 elems
    float4 v0 = ((const float4*)in)[i * 2];
    float4 v1 = ((const float4*)in)[i * 2 + 1];
    bf16x8 o;
    o[0] = f2bf(v0.x); o[1] = f2bf(v0.y); o[2] = f2bf(v0.z); o[3] = f2bf(v0.w);
    o[4] = f2bf(v1.x); o[5] = f2bf(v1.y); o[6] = f2bf(v1.z); o[7] = f2bf(v1.w);
    ((bf16x8*)out)[i] = o;
}

// ---------------------------------------------------------------- pack q_w||kv_w -> bf16 (64,1024)
__global__ __launch_bounds__(256) void qkcvt_kernel(
        const float* __restrict__ qw, const float* __restrict__ kw,
        short* __restrict__ qkw) {
    int i = blockIdx.x * 256 + threadIdx.x;      // per 8 elems, 8192 total
    int n = i >> 7;
    int k8 = (i & 127) * 8;
    const float* src = (n < 32 ? qw + (size_t)n * C_ : kw + (size_t)(n - 32) * C_) + k8;
    float4 v0 = *(const float4*)src;
    float4 v1 = *(const float4*)(src + 4);
    bf16x8 o;
    o[0] = f2bf(v0.x); o[1] = f2bf(v0.y); o[2] = f2bf(v0.z); o[3] = f2bf(v0.w);
    o[4] = f2bf(v1.x); o[5] = f2bf(v1.y); o[6] = f2bf(v1.z); o[7] = f2bf(v1.w);
    ((bf16x8*)qkw)[i] = o;
}

// ---------------------------------------------------------------- q/k proj via MFMA
// tile 128(M) x 64(N=32q+32k), BK=32. grid (B*T)/128.
__global__ __launch_bounds__(256) void qkproj_kernel(
        const short* __restrict__ A, const short* __restrict__ Wq,
        const float* __restrict__ qbias, const float* __restrict__ kbias,
        float* __restrict__ qo, float* __restrict__ ko) {
    __shared__ short At[128 * 32];
    __shared__ short Wt[64 * 32];
    int tid = threadIdx.x;
    int w = tid >> 6, l = tid & 63;
    int i0 = blockIdx.x * 128;
    int R0 = w * 32;
    const int xorb = (((l >> 4) ^ (l & 3)) << 4);
    int srow = l >> 2, schunk = l & 3;

    f32x4 acc[2][4];
#pragma unroll
    for (int m = 0; m < 2; m++)
#pragma unroll
        for (int n = 0; n < 4; n++) acc[m][n] = (f32x4){0.f, 0.f, 0.f, 0.f};

    for (int k0 = 0; k0 < C_; k0 += 32) {
#pragma unroll
        for (int half = 0; half < 2; half++) {
            int rr = half * 64 + w * 16 + srow;
            int gch = schunk ^ (rr & 3);
            async16((const char*)(A + (size_t)(i0 + rr) * C_ + k0) + gch * 16,
                    (char*)At + half * 4096 + w * 1024);
        }
        {
            int rr = w * 16 + srow;
            int gch = schunk ^ (rr & 3);
            async16((const char*)(Wq + (size_t)rr * C_ + k0) + gch * 16,
                    (char*)Wt + w * 1024);
        }
        __syncthreads();
        bf16x8 afr[2], bfr[4];
#pragma unroll
        for (int m = 0; m < 2; m++)
            afr[m] = *(const bf16x8*)((char*)At + (R0 + m * 16 + (l & 15)) * 64 + xorb);
#pragma unroll
        for (int n = 0; n < 4; n++)
            bfr[n] = *(const bf16x8*)((char*)Wt + (n * 16 + (l & 15)) * 64 + xorb);
#pragma unroll
        for (int m = 0; m < 2; m++)
#pragma unroll
            for (int n = 0; n < 4; n++)
                acc[m][n] = __builtin_amdgcn_mfma_f32_16x16x32_bf16(afr[m], bfr[n], acc[m][n], 0, 0, 0);
        __syncthreads();
    }
#pragma unroll
    for (int n = 0; n < 4; n++) {
        int col = n * 16 + (l & 15);
        float bj = (col < 32) ? qbias[col] : kbias[col - 32];
        float* dst = (col < 32) ? qo : ko;
        int cc = col & 31;
#pragma unroll
        for (int m = 0; m < 2; m++) {
            int rbase = i0 + R0 + m * 16 + ((l >> 4) << 2);
#pragma unroll
            for (int g = 0; g < 4; g++)
                dst[(size_t)(rbase + g) * 32 + cc] = acc[m][n][g] + bj;
        }
    }
}

// ---------------------------------------------------------------- V transpose: x (B,T,C) -> xvt (B*H, 64, T) bf16
__global__ __launch_bounds__(256) void vtrans_kernel(
        const float* __restrict__ x, short* __restrict__ xvt) {
    int bh = blockIdx.y;
    int b = bh >> 4, h = bh & 15;
    int t0 = blockIdx.x * 64;
    __shared__ float ldsT[64][65];
    int tid = threadIdx.x;
    int tl = tid >> 2;
    int d0 = (tid & 3) * 16;
    const float* xp = x + ((size_t)(b * T_ + t0 + tl)) * C_ + h * 64 + d0;
#pragma unroll
    for (int q = 0; q < 4; q++) {
        float4 v = *(const float4*)(xp + q * 4);
        ldsT[d0 + q * 4 + 0][tl] = v.x;
        ldsT[d0 + q * 4 + 1][tl] = v.y;
        ldsT[d0 + q * 4 + 2][tl] = v.z;
        ldsT[d0 + q * 4 + 3][tl] = v.w;
    }
    __syncthreads();
    int d = tid >> 2;
    int ts = (tid & 3) * 16;
    short* op = xvt + ((size_t)bh * 64 + d) * T_ + t0 + ts;
    bf16x8 o0, o1;
#pragma unroll
    for (int q = 0; q < 8; q++) {
        o0[q] = f2bf(ldsT[d][ts + q]);
        o1[q] = f2bf(ldsT[d][ts + 8 + q]);
    }
    *(bf16x8*)op = o0;
    *(bf16x8*)(op + 8) = o1;
}

// ---------------------------------------------------------------- attention (MFMA PV)
__global__ __launch_bounds__(256) void attn_kernel(
        const float* __restrict__ qbuf, const float* __restrict__ kbuf,
        const short* __restrict__ xvt, float* __restrict__ xatt) {
    int bh = blockIdx.y;
    int b = bh >> 4, h = bh & 15;
    int t0 = ((int)gridDim.x - 1 - (int)blockIdx.x) * 128;
    int tid = threadIdx.x;
    int w = tid >> 6, l = tid & 63;

    __shared__ short P_lds[128 * 32];
    __shared__ short V_lds[2][64 * 32];
    __shared__ float2 kt[2][32];
    __shared__ float red_lds[128];

    const float scale = 0.02209708691f;     // 1/sqrt(2048)
    int r = tid >> 1, jh = tid & 1;
    int tglob = t0 + r;
    float2 q2 = *(const float2*)(qbuf + ((size_t)(b * T_ + tglob)) * 32 + h * 2);
    float q0 = q2.x * scale, q1 = q2.y * scale;
    float mrun = -1e30f, lrun = 0.f;

    f32x4 acc[2][4];
#pragma unroll
    for (int m = 0; m < 2; m++)
#pragma unroll
        for (int n = 0; n < 4; n++) acc[m][n] = (f32x4){0.f, 0.f, 0.f, 0.f};

    int R0 = w * 32;
    const int xorb = (((l >> 4) ^ (l & 3)) << 4);
    char* Pb = (char*)P_lds;
    char* Vb = (char*)V_lds;

    int dl = l >> 2;
    int d = w * 16 + dl;
    int chunk = l & 3;
    const char* vsrc_base = (const char*)xvt + (((size_t)bh * 64 + d) * T_) * 2
                            + (((chunk ^ (dl & 3)) << 3)) * 2;
    int nt = t0 / 32 + 4;

    if (tid < 32) kt[0][tid] = *(const float2*)(kbuf + ((size_t)(b * T_ + tid)) * 32 + h * 2);
    async16(vsrc_base, Vb + w * 1024);

    for (int t = 0; t < nt; t++) {
        int buf = t & 1;
        __syncthreads();
        if (t + 1 < nt) {
            int s0n = (t + 1) * 32;
            if (tid < 32)
                kt[buf ^ 1][tid] = *(const float2*)(kbuf + ((size_t)(b * T_ + s0n + tid)) * 32 + h * 2);
            async16(vsrc_base + (size_t)s0n * 2, Vb + (buf ^ 1) * 4096 + w * 1024);
        }
        int s0 = t * 32;
        int jbase = jh * 16;
        float s_[16];
        float tm = -1e30f;
#pragma unroll
        for (int jj = 0; jj < 16; jj++) {
            float2 k2 = kt[buf][jbase + jj];
            float sc = fmaf(q0, k2.x, q1 * k2.y);
            sc = (s0 + jbase + jj <= tglob) ? sc : -1e30f;
            s_[jj] = sc;
            tm = fmaxf(tm, sc);
        }
        tm = fmaxf(tm, __shfl_xor(tm, 1));
        float nm = fmaxf(mrun, tm);
        float corr = __expf(mrun - nm);
        mrun = nm;
        float ls = 0.f;
        bf16x8 c0, c1;
#pragma unroll
        for (int jj = 0; jj < 8; jj++) {
            float p = __expf(s_[jj] - nm);
            ls += p;
            c0[jj] = f2bf(p);
        }
#pragma unroll
        for (int jj = 8; jj < 16; jj++) {
            float p = __expf(s_[jj] - nm);
            ls += p;
            c1[jj - 8] = f2bf(p);
        }
        ls += __shfl_xor(ls, 1);
        lrun = lrun * corr + ls;
        if (jh == 0) red_lds[r] = corr;
        int cw0 = jh * 2, cw1 = jh * 2 + 1;
        *(bf16x8*)(Pb + r * 64 + (((cw0 ^ (r & 3)) << 4))) = c0;
        *(bf16x8*)(Pb + r * 64 + (((cw1 ^ (r & 3)) << 4))) = c1;
#pragma unroll
        for (int m = 0; m < 2; m++) {
#pragma unroll
            for (int g = 0; g < 4; g++) {
                float cc = red_lds[R0 + m * 16 + ((l >> 4) << 2) + g];
#pragma unroll
                for (int n = 0; n < 4; n++) acc[m][n][g] *= cc;
            }
        }
        bf16x8 afr[2], bfr[4];
#pragma unroll
        for (int m = 0; m < 2; m++)
            afr[m] = *(const bf16x8*)(Pb + (R0 + m * 16 + (l & 15)) * 64 + xorb);
#pragma unroll
        for (int n = 0; n < 4; n++)
            bfr[n] = *(const bf16x8*)(Vb + buf * 4096 + (n * 16 + (l & 15)) * 64 + xorb);
#pragma unroll
        for (int m = 0; m < 2; m++)
#pragma unroll
            for (int n = 0; n < 4; n++)
                acc[m][n] = __builtin_amdgcn_mfma_f32_16x16x32_bf16(afr[m], bfr[n], acc[m][n], 0, 0, 0);
    }
    if (jh == 0) red_lds[r] = lrun;
#pragma unroll
    for (int m = 0; m < 2; m++) {
#pragma unroll
        for (int g = 0; g < 4; g++) {
            int row = R0 + m * 16 + ((l >> 4) << 2) + g;
            float inv = 1.f / red_lds[row];
            int trow = t0 + row;
#pragma unroll
            for (int n = 0; n < 4; n++) {
                int col = h * 64 + n * 16 + (l & 15);
                xatt[((size_t)(b * T_ + trow)) * C_ + col] = acc[m][n][g] * inv;
            }
        }
    }
}

// ---------------------------------------------------------------- bf16 MFMA GEMM  out = A(M,K)*W(N,K)^T
template <int MODE>
__global__ __launch_bounds__(256) void mgemm_kernel(
        const short* __restrict__ A, const short* __restrict__ W,
        const float* __restrict__ bias, short* __restrict__ outb,
        float* __restrict__ out32,
        const float* __restrict__ e0, const float* __restrict__ e1,
        const float* __restrict__ e2, const float* __restrict__ e3) {
    __shared__ short At[128 * 32];
    __shared__ short Wt[64 * 32];
    int tid = threadIdx.x;
    int w = tid >> 6, l = tid & 63;
    int i0 = blockIdx.y * 128, j0 = blockIdx.x * 64;
    int R0 = w * 32;
    const int xorb = (((l >> 4) ^ (l & 3)) << 4);
    int srow = l >> 2, schunk = l & 3;

    f32x4 acc[2][4];
#pragma unroll
    for (int m = 0; m < 2; m++)
#pragma unroll
        for (int n = 0; n < 4; n++) acc[m][n] = (f32x4){0.f, 0.f, 0.f, 0.f};

    for (int k0 = 0; k0 < C_; k0 += 32) {
#pragma unroll
        for (int half = 0; half < 2; half++) {
            int rr = half * 64 + w * 16 + srow;
            int gch = schunk ^ (rr & 3);
            async16((const char*)(A + (size_t)(i0 + rr) * C_ + k0) + gch * 16,
                    (char*)At + half * 4096 + w * 1024);
        }
        {
            int rr = w * 16 + srow;
            int gch = schunk ^ (rr & 3);
            async16((const char*)(W + (size_t)(j0 + rr) * C_ + k0) + gch * 16,
                    (char*)Wt + w * 1024);
        }
        __syncthreads();
        bf16x8 afr[2], bfr[4];
#pragma unroll
        for (int m = 0; m < 2; m++)
            afr[m] = *(const bf16x8*)((char*)At + (R0 + m * 16 + (l & 15)) * 64 + xorb);
#pragma unroll
        for (int n = 0; n < 4; n++)
            bfr[n] = *(const bf16x8*)((char*)Wt + (n * 16 + (l & 15)) * 64 + xorb);
#pragma unroll
        for (int m = 0; m < 2; m++)
#pragma unroll
            for (int n = 0; n < 4; n++)
                acc[m][n] = __builtin_amdgcn_mfma_f32_16x16x32_bf16(afr[m], bfr[n], acc[m][n], 0, 0, 0);
        __syncthreads();
    }
#pragma unroll
    for (int n = 0; n < 4; n++) {
        int col = j0 + n * 16 + (l & 15);
        float bj = bias[col];
        float tdv = (MODE == 1) ? e3[col] : 0.f;
#pragma unroll
        for (int m = 0; m < 2; m++) {
            int rbase = i0 + R0 + m * 16 + ((l >> 4) << 2);
#pragma unroll
            for (int g = 0; g < 4; g++) {
                size_t off = (size_t)(rbase + g) * C_ + col;
                float z = acc[m][n][g] + bj;
                if (MODE == 0) {
                    z = z / (1.f + __expf(-z));
                    outb[off] = f2bf(z);
                } else if (MODE == 1) {
                    float comb = e0[off] + 0.5f * e1[off] + 0.5f * z;
                    z = comb * tdv + e2[off] * (1.f - tdv);
                    outb[off] = f2bf(z);
                } else {
                    out32[off] = z;
                }
            }
        }
    }
}

// ---------------------------------------------------------------- layernorm + residual
__global__ __launch_bounds__(256) void ln_kernel(
        const float* __restrict__ proj, const float* __restrict__ x,
        const float* __restrict__ g, const float* __restrict__ bb,
        float* __restrict__ out) {
    int row = blockIdx.x;
    int tid = threadIdx.x;
    const float* pr = proj + (size_t)row * C_;
    float4 v = *(const float4*)(pr + tid * 4);
    float s = v.x + v.y + v.z + v.w;
    float s2 = v.x * v.x + v.y * v.y + v.z * v.z + v.w * v.w;
#pragma unroll
    for (int off = 32; off > 0; off >>= 1) {
        s += __shfl_down(s, off);
        s2 += __shfl_down(s2, off);
    }
    __shared__ float ws0[4], ws1[4];
    int wid = tid >> 6;
    if ((tid & 63) == 0) { ws0[wid] = s; ws1[wid] = s2; }
    __syncthreads();
    s = ws0[0] + ws0[1] + ws0[2] + ws0[3];
    s2 = ws1[0] + ws1[1] + ws1[2] + ws1[3];
    float mu = s * (1.f / C_);
    float var = s2 * (1.f / C_) - mu * mu;
    float rs = rsqrtf(var + 1e-5f);
    int c = tid * 4;
    float4 xr = *(const float4*)(x + (size_t)row * C_ + c);
    float4 gg = *(const float4*)(g + c);
    float4 bv = *(const float4*)(bb + c);
    float4 o;
    o.x = (v.x - mu) * rs * gg.x + bv.x + xr.x;
    o.y = (v.y - mu) * rs * gg.y + bv.y + xr.y;
    o.z = (v.z - mu) * rs * gg.z + bv.z + xr.z;
    o.w = (v.w - mu) * rs * gg.w + bv.w + xr.w;
    *(float4*)(out + (size_t)row * C_ + c) = o;
}

// ---------------------------------------------------------------- launch
extern "C" void kernel_launch(void* const* d_in, const int* in_sizes, int n_in,
                              void* d_out, int out_size, void* d_ws, size_t ws_size,
                              hipStream_t stream) {
    const float* x      = (const float*)d_in[0];
    const float* conv_w = (const float*)d_in[1];
    const float* conv_b = (const float*)d_in[2];
    const float* q_w    = (const float*)d_in[3];
    const float* q_b    = (const float*)d_in[4];
    const float* kv_w   = (const float*)d_in[5];
    const float* kv_b   = (const float*)d_in[6];
    const float* mem_w1 = (const float*)d_in[7];
    const float* mem_b1 = (const float*)d_in[8];
    const float* mem_w2 = (const float*)d_in[9];
    const float* mem_b2 = (const float*)d_in[10];
    const float* out_w  = (const float*)d_in[11];
    const float* out_b  = (const float*)d_in[12];
    const float* ln_g   = (const float*)d_in[13];
    const float* ln_b   = (const float*)d_in[14];
    const float* td     = (const float*)d_in[15];
    float* out = (float*)d_out;

    const size_t NTC = (size_t)B_ * T_ * C_;      // 4M
    char* p = (char*)d_ws;
    float* xconv = (float*)p;            p += NTC * 4;
    float* xatt  = (float*)p;            p += NTC * 4;
    float* proj  = (float*)p;            p += NTC * 4;
    float* qb_   = (float*)p;            p += (size_t)B_ * T_ * 32 * 4;
    float* kb_   = (float*)p;            p += (size_t)B_ * T_ * 32 * 4;
    short* xbf   = (short*)p;            p += NTC * 2;
    short* y1bf  = (short*)p;            p += NTC * 2;
    short* combbf= (short*)p;            p += NTC * 2;
    short* xvt   = (short*)p;            p += NTC * 2;
    short* wbf1  = (short*)p;            p += (size_t)C_ * C_ * 2;
    short* wbf2  = (short*)p;            p += (size_t)C_ * C_ * 2;
    short* wbf3  = (short*)p;            p += (size_t)C_ * C_ * 2;
    short* qkw   = (short*)p;            p += (size_t)64 * C_ * 2;

    const int WN8 = (C_ * C_) / 8 / 256;
    cvt_kernel<<<(int)(NTC / 8 / 256), 256, 0, stream>>>(x, xbf);
    cvt_kernel<<<WN8, 256, 0, stream>>>(mem_w1, wbf1);
    cvt_kernel<<<WN8, 256, 0, stream>>>(mem_w2, wbf2);
    cvt_kernel<<<WN8, 256, 0, stream>>>(out_w, wbf3);
    qkcvt_kernel<<<(64 * C_) / 8 / 256, 256, 0, stream>>>(q_w, kv_w, qkw);
    vtrans_kernel<<<dim3(T_ / 64, B_ * H_), 256, 0, stream>>>(x, xvt);
    conv_kernel<<<dim3(T_ / TCV, B_ * (C_ / 256)), 256, 0, stream>>>(x, conv_w, conv_b, xconv);
    qkproj_kernel<<<(B_ * T_) / 128, 256, 0, stream>>>(xbf, qkw, q_b, kv_b, qb_, kb_);
    attn_kernel<<<dim3(T_ / 128, B_ * H_), 256, 0, stream>>>(qb_, kb_, xvt, xatt);
    mgemm_kernel<0><<<dim3(C_ / 64, (B_ * T_) / 128), 256, 0, stream>>>(
        xbf, wbf1, mem_b1, y1bf, nullptr, nullptr, nullptr, nullptr, nullptr);
    mgemm_kernel<1><<<dim3(C_ / 64, (B_ * T_) / 128), 256, 0, stream>>>(
        y1bf, wbf2, mem_b2, combbf, nullptr, xconv, xatt, x, td);
    mgemm_kernel<2><<<dim3(C_ / 64, (B_ * T_) / 128), 256, 0, stream>>>(
        combbf, wbf3, out_b, nullptr, proj, nullptr, nullptr, nullptr, nullptr);
    ln_kernel<<<B_ * T_, 256, 0, stream>>>(proj, x, ln_g, ln_b, out);
}

// Round 4
// 184.230 us; speedup vs baseline: 6.1464x; 1.1557x over previous
//
#include <hip/hip_runtime.h>
#include <hip/hip_bf16.h>

#define B_ 2
#define T_ 2048
#define C_ 1024
#define H_ 16
#define DV_ 64
#define KW_ 31

typedef __attribute__((ext_vector_type(8))) short bf16x8;
typedef __attribute__((ext_vector_type(4))) float f32x4;

__device__ inline short f2bf(float f) {
    __hip_bfloat16 h = __float2bfloat16(f);
    return *reinterpret_cast<short*>(&h);
}

__device__ inline void async16(const void* g, void* l) {
    __builtin_amdgcn_global_load_lds(
        (const __attribute__((address_space(1))) unsigned int*)g,
        (__attribute__((address_space(3))) unsigned int*)l, 16, 0, 0);
}

// ---------------------------------------------------------------- conv (register sliding window)
#define TCV 32
__global__ __launch_bounds__(256) void conv_kernel(
        const float* __restrict__ x, const float* __restrict__ w,
        const float* __restrict__ bias, float* __restrict__ out) {
    int b = blockIdx.y >> 2;
    int c0 = (blockIdx.y & 3) * 256;
    int t0 = blockIdx.x * TCV;
    int tid = threadIdx.x;
    __shared__ float wl[256 * KW_];
    for (int i = tid; i < 256 * KW_; i += 256) wl[i] = w[c0 * KW_ + i];
    __syncthreads();
    float wr[KW_];
#pragma unroll
    for (int k = 0; k < KW_; k++) wr[k] = wl[tid * KW_ + k];
    int c = c0 + tid;
    float bi = bias[c];
    float acc[TCV];
#pragma unroll
    for (int t = 0; t < TCV; t++) acc[t] = bi;
    const float* xp = x + (size_t)b * T_ * C_ + c;
#pragma unroll
    for (int i = 0; i < TCV + KW_ - 1; i++) {
        int tt = t0 + i - 15;
        float xv = (tt >= 0 && tt < T_) ? xp[(size_t)tt * C_] : 0.f;
        int lo = (i - (KW_ - 1) > 0) ? i - (KW_ - 1) : 0;
        int hi = (i < TCV - 1) ? i : TCV - 1;
#pragma unroll
        for (int t = lo; t <= hi; t++)
            acc[t] = fmaf(xv, wr[i - t], acc[t]);
    }
    float* op = out + ((size_t)b * T_ + t0) * C_ + c;
#pragma unroll
    for (int t = 0; t < TCV; t++) op[(size_t)t * C_] = acc[t];
}

// ---------------------------------------------------------------- f32 -> bf16
__global__ __launch_bounds__(256) void cvt_kernel(
        const float* __restrict__ in, short* __restrict__ out) {
    int i = blockIdx.x * 256 + threadIdx.x;
    float4 v0 = ((const float4*)in)[i * 2];
    float4 v1 = ((const float4*)in)[i * 2 + 1];
    bf16x8 o;
    o[0] = f2bf(v0.x); o[1] = f2bf(v0.y); o[2] = f2bf(v0.z); o[3] = f2bf(v0.w);
    o[4] = f2bf(v1.x); o[5] = f2bf(v1.y); o[6] = f2bf(v1.z); o[7] = f2bf(v1.w);
    ((bf16x8*)out)[i] = o;
}

// ---------------------------------------------------------------- pack q_w||kv_w -> bf16 (64,1024)
__global__ __launch_bounds__(256) void qkcvt_kernel(
        const float* __restrict__ qw, const float* __restrict__ kw,
        short* __restrict__ qkw) {
    int i = blockIdx.x * 256 + threadIdx.x;
    int n = i >> 7;
    int k8 = (i & 127) * 8;
    const float* src = (n < 32 ? qw + (size_t)n * C_ : kw + (size_t)(n - 32) * C_) + k8;
    float4 v0 = *(const float4*)src;
    float4 v1 = *(const float4*)(src + 4);
    bf16x8 o;
    o[0] = f2bf(v0.x); o[1] = f2bf(v0.y); o[2] = f2bf(v0.z); o[3] = f2bf(v0.w);
    o[4] = f2bf(v1.x); o[5] = f2bf(v1.y); o[6] = f2bf(v1.z); o[7] = f2bf(v1.w);
    ((bf16x8*)qkw)[i] = o;
}

// ---------------------------------------------------------------- q/k proj via MFMA
__global__ __launch_bounds__(256) void qkproj_kernel(
        const short* __restrict__ A, const short* __restrict__ Wq,
        const float* __restrict__ qbias, const float* __restrict__ kbias,
        float* __restrict__ qo, float* __restrict__ ko) {
    __shared__ short At[128 * 32];
    __shared__ short Wt[64 * 32];
    int tid = threadIdx.x;
    int w = tid >> 6, l = tid & 63;
    int i0 = blockIdx.x * 128;
    int R0 = w * 32;
    const int xorb = (((l >> 4) ^ (l & 3)) << 4);
    int srow = l >> 2, schunk = l & 3;

    f32x4 acc[2][4];
#pragma unroll
    for (int m = 0; m < 2; m++)
#pragma unroll
        for (int n = 0; n < 4; n++) acc[m][n] = (f32x4){0.f, 0.f, 0.f, 0.f};

    for (int k0 = 0; k0 < C_; k0 += 32) {
#pragma unroll
        for (int half = 0; half < 2; half++) {
            int rr = half * 64 + w * 16 + srow;
            int gch = schunk ^ (rr & 3);
            async16((const char*)(A + (size_t)(i0 + rr) * C_ + k0) + gch * 16,
                    (char*)At + half * 4096 + w * 1024);
        }
        {
            int rr = w * 16 + srow;
            int gch = schunk ^ (rr & 3);
            async16((const char*)(Wq + (size_t)rr * C_ + k0) + gch * 16,
                    (char*)Wt + w * 1024);
        }
        __syncthreads();
        bf16x8 afr[2], bfr[4];
#pragma unroll
        for (int m = 0; m < 2; m++)
            afr[m] = *(const bf16x8*)((char*)At + (R0 + m * 16 + (l & 15)) * 64 + xorb);
#pragma unroll
        for (int n = 0; n < 4; n++)
            bfr[n] = *(const bf16x8*)((char*)Wt + (n * 16 + (l & 15)) * 64 + xorb);
#pragma unroll
        for (int m = 0; m < 2; m++)
#pragma unroll
            for (int n = 0; n < 4; n++)
                acc[m][n] = __builtin_amdgcn_mfma_f32_16x16x32_bf16(afr[m], bfr[n], acc[m][n], 0, 0, 0);
        __syncthreads();
    }
#pragma unroll
    for (int n = 0; n < 4; n++) {
        int col = n * 16 + (l & 15);
        float bj = (col < 32) ? qbias[col] : kbias[col - 32];
        float* dst = (col < 32) ? qo : ko;
        int cc = col & 31;
#pragma unroll
        for (int m = 0; m < 2; m++) {
            int rbase = i0 + R0 + m * 16 + ((l >> 4) << 2);
#pragma unroll
            for (int g = 0; g < 4; g++)
                dst[(size_t)(rbase + g) * 32 + cc] = acc[m][n][g] + bj;
        }
    }
}

// ---------------------------------------------------------------- V transpose: x (B,T,C) -> xvt (B*H, 64, T) bf16
__global__ __launch_bounds__(256) void vtrans_kernel(
        const float* __restrict__ x, short* __restrict__ xvt) {
    int bh = blockIdx.y;
    int b = bh >> 4, h = bh & 15;
    int t0 = blockIdx.x * 64;
    __shared__ float ldsT[64][65];
    int tid = threadIdx.x;
    int tl = tid >> 2;
    int d0 = (tid & 3) * 16;
    const float* xp = x + ((size_t)(b * T_ + t0 + tl)) * C_ + h * 64 + d0;
#pragma unroll
    for (int q = 0; q < 4; q++) {
        float4 v = *(const float4*)(xp + q * 4);
        ldsT[d0 + q * 4 + 0][tl] = v.x;
        ldsT[d0 + q * 4 + 1][tl] = v.y;
        ldsT[d0 + q * 4 + 2][tl] = v.z;
        ldsT[d0 + q * 4 + 3][tl] = v.w;
    }
    __syncthreads();
    int d = tid >> 2;
    int ts = (tid & 3) * 16;
    short* op = xvt + ((size_t)bh * 64 + d) * T_ + t0 + ts;
    bf16x8 o0, o1;
#pragma unroll
    for (int q = 0; q < 8; q++) {
        o0[q] = f2bf(ldsT[d][ts + q]);
        o1[q] = f2bf(ldsT[d][ts + 8 + q]);
    }
    *(bf16x8*)op = o0;
    *(bf16x8*)(op + 8) = o1;
}

// ---------------------------------------------------------------- attention (MFMA PV, no-max softmax)
// 64 q-rows/block, 256 thr, KV tile 64. Softmax: row=tid>>2, quarter=tid&3.
// MFMA: wave w rows w*16..+15 (wave-local P), cols 0..63.
__global__ __launch_bounds__(256) void attn_kernel(
        const float* __restrict__ qbuf, const float* __restrict__ kbuf,
        const short* __restrict__ xvt, float* __restrict__ xatt) {
    int bh = blockIdx.y;
    int b = bh >> 4, h = bh & 15;
    int t0 = ((int)gridDim.x - 1 - (int)blockIdx.x) * 64;
    int tid = threadIdx.x;
    int w = tid >> 6, l = tid & 63;

    __shared__ short P_lds[64 * 64];        // 8KB, rows 128B, slot^= row&7
    __shared__ short V_lds[2 * 64 * 64];    // 2x8KB
    __shared__ float2 kt[2][64];
    __shared__ float red_lds[64];

    // fold 1/sqrt(T) * log2(e) into q so exp2 is direct
    const float scale = 0.02209708691f * 1.44269504089f;
    int r = tid >> 2, jq = tid & 3;
    int tglob = t0 + r;
    float2 q2 = *(const float2*)(qbuf + ((size_t)(b * T_ + tglob)) * 32 + h * 2);
    float q0 = q2.x * scale, q1 = q2.y * scale;
    float lrun = 0.f;

    f32x4 acc[4];
#pragma unroll
    for (int n = 0; n < 4; n++) acc[n] = (f32x4){0.f, 0.f, 0.f, 0.f};

    int R0 = w * 16;
    char* Pb = (char*)P_lds;
    char* Vb = (char*)V_lds;

    // V staging geometry: call q covers rows q*32 + w*8 .. +7
    int dq0 = (l >> 3);                     // 0..7 row within group
    int kch = (l & 7) ^ dq0;                // unswizzled k-chunk this lane fetches
    const char* vsrc0 = (const char*)xvt + (((size_t)bh * 64 + (w * 8 + dq0)) * T_ + kch * 8) * 2;
    const char* vsrc1 = (const char*)xvt + (((size_t)bh * 64 + (32 + w * 8 + dq0)) * T_ + kch * 8) * 2;

    int nt = t0 / 64 + 1;

    // prologue: stage tile 0 -> buf 0
    if (tid < 64) kt[0][tid] = *(const float2*)(kbuf + ((size_t)(b * T_ + tid)) * 32 + h * 2);
    async16(vsrc0, Vb + w * 1024);
    async16(vsrc1, Vb + 4096 + w * 1024);

    for (int t = 0; t < nt; t++) {
        int buf = t & 1;
        __syncthreads();
        if (t + 1 < nt) {
            int s0n = (t + 1) * 64;
            if (tid < 64)
                kt[buf ^ 1][tid] = *(const float2*)(kbuf + ((size_t)(b * T_ + s0n + tid)) * 32 + h * 2);
            async16(vsrc0 + (size_t)s0n * 2, Vb + (buf ^ 1) * 8192 + w * 1024);
            async16(vsrc1 + (size_t)s0n * 2, Vb + (buf ^ 1) * 8192 + 4096 + w * 1024);
        }
        // ---- softmax role: 16 scores, no max-tracking (scores bounded ~0.4)
        int jbase = jq * 16;
        float ls = 0.f;
        bf16x8 c0, c1;
        bool diag = (t == nt - 1);
#pragma unroll
        for (int jj = 0; jj < 16; jj++) {
            float2 k2 = kt[buf][jbase + jj];
            float sc = fmaf(q0, k2.x, q1 * k2.y);
            if (diag) sc = (jbase + jj <= r) ? sc : -100.f;
            float p = exp2f(sc);
            ls += p;
            if (jj < 8) c0[jj] = f2bf(p); else c1[jj - 8] = f2bf(p);
        }
        ls += __shfl_xor(ls, 1);
        ls += __shfl_xor(ls, 2);
        lrun += ls;
        *(bf16x8*)(Pb + r * 128 + ((((jq * 2)     ) ^ (r & 7)) << 4)) = c0;
        *(bf16x8*)(Pb + r * 128 + ((((jq * 2) + 1 ) ^ (r & 7)) << 4)) = c1;
        // ---- MFMA role (wave-local P)
        int rowA = l & 15;
        int l7 = l & 7;
        bf16x8 afr[2], bfr[4][2];
#pragma unroll
        for (int ks = 0; ks < 2; ks++)
            afr[ks] = *(const bf16x8*)(Pb + (R0 + rowA) * 128 + ((((l >> 4) + ks * 4) ^ l7) << 4));
#pragma unroll
        for (int n = 0; n < 4; n++)
#pragma unroll
            for (int ks = 0; ks < 2; ks++)
                bfr[n][ks] = *(const bf16x8*)(Vb + buf * 8192 + (n * 16 + rowA) * 128 + ((((l >> 4) + ks * 4) ^ l7) << 4));
#pragma unroll
        for (int n = 0; n < 4; n++) {
            acc[n] = __builtin_amdgcn_mfma_f32_16x16x32_bf16(afr[0], bfr[n][0], acc[n], 0, 0, 0);
            acc[n] = __builtin_amdgcn_mfma_f32_16x16x32_bf16(afr[1], bfr[n][1], acc[n], 0, 0, 0);
        }
    }
    // epilogue
    if (jq == 0) red_lds[r] = lrun;
#pragma unroll
    for (int g = 0; g < 4; g++) {
        int row = R0 + ((l >> 4) << 2) + g;
        float inv = 1.f / red_lds[row];
        int trow = t0 + row;
#pragma unroll
        for (int n = 0; n < 4; n++) {
            int col = h * 64 + n * 16 + (l & 15);
            xatt[((size_t)(b * T_ + trow)) * C_ + col] = acc[n][g] * inv;
        }
    }
}

// ---------------------------------------------------------------- bf16 MFMA GEMM  out = A(M,K)*W(N,K)^T
template <int MODE>
__global__ __launch_bounds__(256) void mgemm_kernel(
        const short* __restrict__ A, const short* __restrict__ W,
        const float* __restrict__ bias, short* __restrict__ outb,
        float* __restrict__ out32,
        const float* __restrict__ e0, const float* __restrict__ e1,
        const float* __restrict__ e2, const float* __restrict__ e3) {
    __shared__ short At[128 * 32];
    __shared__ short Wt[64 * 32];
    int tid = threadIdx.x;
    int w = tid >> 6, l = tid & 63;
    int i0 = blockIdx.y * 128, j0 = blockIdx.x * 64;
    int R0 = w * 32;
    const int xorb = (((l >> 4) ^ (l & 3)) << 4);
    int srow = l >> 2, schunk = l & 3;

    f32x4 acc[2][4];
#pragma unroll
    for (int m = 0; m < 2; m++)
#pragma unroll
        for (int n = 0; n < 4; n++) acc[m][n] = (f32x4){0.f, 0.f, 0.f, 0.f};

    for (int k0 = 0; k0 < C_; k0 += 32) {
#pragma unroll
        for (int half = 0; half < 2; half++) {
            int rr = half * 64 + w * 16 + srow;
            int gch = schunk ^ (rr & 3);
            async16((const char*)(A + (size_t)(i0 + rr) * C_ + k0) + gch * 16,
                    (char*)At + half * 4096 + w * 1024);
        }
        {
            int rr = w * 16 + srow;
            int gch = schunk ^ (rr & 3);
            async16((const char*)(W + (size_t)(j0 + rr) * C_ + k0) + gch * 16,
                    (char*)Wt + w * 1024);
        }
        __syncthreads();
        bf16x8 afr[2], bfr[4];
#pragma unroll
        for (int m = 0; m < 2; m++)
            afr[m] = *(const bf16x8*)((char*)At + (R0 + m * 16 + (l & 15)) * 64 + xorb);
#pragma unroll
        for (int n = 0; n < 4; n++)
            bfr[n] = *(const bf16x8*)((char*)Wt + (n * 16 + (l & 15)) * 64 + xorb);
#pragma unroll
        for (int m = 0; m < 2; m++)
#pragma unroll
            for (int n = 0; n < 4; n++)
                acc[m][n] = __builtin_amdgcn_mfma_f32_16x16x32_bf16(afr[m], bfr[n], acc[m][n], 0, 0, 0);
        __syncthreads();
    }
#pragma unroll
    for (int n = 0; n < 4; n++) {
        int col = j0 + n * 16 + (l & 15);
        float bj = bias[col];
        float tdv = (MODE == 1) ? e3[col] : 0.f;
#pragma unroll
        for (int m = 0; m < 2; m++) {
            int rbase = i0 + R0 + m * 16 + ((l >> 4) << 2);
#pragma unroll
            for (int g = 0; g < 4; g++) {
                size_t off = (size_t)(rbase + g) * C_ + col;
                float z = acc[m][n][g] + bj;
                if (MODE == 0) {
                    z = z / (1.f + __expf(-z));
                    outb[off] = f2bf(z);
                } else if (MODE == 1) {
                    float comb = e0[off] + 0.5f * e1[off] + 0.5f * z;
                    z = comb * tdv + e2[off] * (1.f - tdv);
                    outb[off] = f2bf(z);
                } else {
                    out32[off] = z;
                }
            }
        }
    }
}

// ---------------------------------------------------------------- layernorm + residual
__global__ __launch_bounds__(256) void ln_kernel(
        const float* __restrict__ proj, const float* __restrict__ x,
        const float* __restrict__ g, const float* __restrict__ bb,
        float* __restrict__ out) {
    int row = blockIdx.x;
    int tid = threadIdx.x;
    const float* pr = proj + (size_t)row * C_;
    float4 v = *(const float4*)(pr + tid * 4);
    float s = v.x + v.y + v.z + v.w;
    float s2 = v.x * v.x + v.y * v.y + v.z * v.z + v.w * v.w;
#pragma unroll
    for (int off = 32; off > 0; off >>= 1) {
        s += __shfl_down(s, off);
        s2 += __shfl_down(s2, off);
    }
    __shared__ float ws0[4], ws1[4];
    int wid = tid >> 6;
    if ((tid & 63) == 0) { ws0[wid] = s; ws1[wid] = s2; }
    __syncthreads();
    s = ws0[0] + ws0[1] + ws0[2] + ws0[3];
    s2 = ws1[0] + ws1[1] + ws1[2] + ws1[3];
    float mu = s * (1.f / C_);
    float var = s2 * (1.f / C_) - mu * mu;
    float rs = rsqrtf(var + 1e-5f);
    int c = tid * 4;
    float4 xr = *(const float4*)(x + (size_t)row * C_ + c);
    float4 gg = *(const float4*)(g + c);
    float4 bv = *(const float4*)(bb + c);
    float4 o;
    o.x = (v.x - mu) * rs * gg.x + bv.x + xr.x;
    o.y = (v.y - mu) * rs * gg.y + bv.y + xr.y;
    o.z = (v.z - mu) * rs * gg.z + bv.z + xr.z;
    o.w = (v.w - mu) * rs * gg.w + bv.w + xr.w;
    *(float4*)(out + (size_t)row * C_ + c) = o;
}

// ---------------------------------------------------------------- launch
extern "C" void kernel_launch(void* const* d_in, const int* in_sizes, int n_in,
                              void* d_out, int out_size, void* d_ws, size_t ws_size,
                              hipStream_t stream) {
    const float* x      = (const float*)d_in[0];
    const float* conv_w = (const float*)d_in[1];
    const float* conv_b = (const float*)d_in[2];
    const float* q_w    = (const float*)d_in[3];
    const float* q_b    = (const float*)d_in[4];
    const float* kv_w   = (const float*)d_in[5];
    const float* kv_b   = (const float*)d_in[6];
    const float* mem_w1 = (const float*)d_in[7];
    const float* mem_b1 = (const float*)d_in[8];
    const float* mem_w2 = (const float*)d_in[9];
    const float* mem_b2 = (const float*)d_in[10];
    const float* out_w  = (const float*)d_in[11];
    const float* out_b  = (const float*)d_in[12];
    const float* ln_g   = (const float*)d_in[13];
    const float* ln_b   = (const float*)d_in[14];
    const float* td     = (const float*)d_in[15];
    float* out = (float*)d_out;

    const size_t NTC = (size_t)B_ * T_ * C_;      // 4M
    char* p = (char*)d_ws;
    float* xconv = (float*)p;            p += NTC * 4;
    float* xatt  = (float*)p;            p += NTC * 4;
    float* proj  = (float*)p;            p += NTC * 4;
    float* qb_   = (float*)p;            p += (size_t)B_ * T_ * 32 * 4;
    float* kb_   = (float*)p;            p += (size_t)B_ * T_ * 32 * 4;
    short* xbf   = (short*)p;            p += NTC * 2;
    short* y1bf  = (short*)p;            p += NTC * 2;
    short* combbf= (short*)p;            p += NTC * 2;
    short* xvt   = (short*)p;            p += NTC * 2;
    short* wbf1  = (short*)p;            p += (size_t)C_ * C_ * 2;
    short* wbf2  = (short*)p;            p += (size_t)C_ * C_ * 2;
    short* wbf3  = (short*)p;            p += (size_t)C_ * C_ * 2;
    short* qkw   = (short*)p;            p += (size_t)64 * C_ * 2;

    const int WN8 = (C_ * C_) / 8 / 256;
    cvt_kernel<<<(int)(NTC / 8 / 256), 256, 0, stream>>>(x, xbf);
    cvt_kernel<<<WN8, 256, 0, stream>>>(mem_w1, wbf1);
    cvt_kernel<<<WN8, 256, 0, stream>>>(mem_w2, wbf2);
    cvt_kernel<<<WN8, 256, 0, stream>>>(out_w, wbf3);
    qkcvt_kernel<<<(64 * C_) / 8 / 256, 256, 0, stream>>>(q_w, kv_w, qkw);
    vtrans_kernel<<<dim3(T_ / 64, B_ * H_), 256, 0, stream>>>(x, xvt);
    conv_kernel<<<dim3(T_ / TCV, B_ * (C_ / 256)), 256, 0, stream>>>(x, conv_w, conv_b, xconv);
    qkproj_kernel<<<(B_ * T_) / 128, 256, 0, stream>>>(xbf, qkw, q_b, kv_b, qb_, kb_);
    attn_kernel<<<dim3(T_ / 64, B_ * H_), 256, 0, stream>>>(qb_, kb_, xvt, xatt);
    mgemm_kernel<0><<<dim3(C_ / 64, (B_ * T_) / 128), 256, 0, stream>>>(
        xbf, wbf1, mem_b1, y1bf, nullptr, nullptr, nullptr, nullptr, nullptr);
    mgemm_kernel<1><<<dim3(C_ / 64, (B_ * T_) / 128), 256, 0, stream>>>(
        y1bf, wbf2, mem_b2, combbf, nullptr, xconv, xatt, x, td);
    mgemm_kernel<2><<<dim3(C_ / 64, (B_ * T_) / 128), 256, 0, stream>>>(
        combbf, wbf3, out_b, nullptr, proj, nullptr, nullptr, nullptr, nullptr);
    ln_kernel<<<B_ * T_, 256, 0, stream>>>(proj, x, ln_g, ln_b, out);
}